// Round 1
// baseline (245.020 us; speedup 1.0000x reference)
//
#include <hip/hip_runtime.h>

// MPS encoder, segmented-chain formulation with PAIRWISE folding.
// Per 16-batch tile / 16-site segment:
//   build M_a (d-major LDS) and M_b (r-major LDS) via fp8 MFMA,
//   pair-product N = M_a*M_b (fp8 MFMA, writeback lands in A-style N^T),
//   chain fold P <- P*N with P held in REGISTERS as MFMA B-fragments
//   (acc->frag conversion via cvt_pk_fp8 + ds_bpermute, no LDS round trip).
// Chain depth 8 (was 16), 2 barriers/pair (was 4), same MFMA count.
// Scaling: core8 = fp8(16*core); frags hold 16*true values; combine /16 per seg.

#define NSITES 128
#define FEATD  64
#define BOND   32
#define OUTD   256
#define BT     16
#define SEGLEN 16
#define NSEG   (NSITES / SEGLEN)   // 8
#define NPAIR  (SEGLEN / 2)        // 8
#define NBT    (2048 / BT)         // 128

// Row stride 36 (32B + 4 pad): b64-style reads hit banks 9*cl+2q -> <=2-way (free).
// Batch stride 1164 = 32*36+12: /4 = 291 == 3 (mod 32) -> writes <=2-way.
#define RSTRIDE 36
#define BSTRIDE 1164

typedef __attribute__((ext_vector_type(4))) float float4v;

__device__ __forceinline__ unsigned pk4_fp8(float a, float b, float c, float d) {
    int v = __builtin_amdgcn_cvt_pk_fp8_f32(a, b, 0, false);
    v = __builtin_amdgcn_cvt_pk_fp8_f32(c, d, v, true);
    return (unsigned)v;
}

// 8-byte LDS load as two dwords (addresses are only 4-aligned with RSTRIDE 36;
// compiler emits ds_read2_b32 / ds_read_b32 pairs).
__device__ __forceinline__ long ld8(const unsigned char* p) {
    unsigned lo = *(const unsigned*)p;
    unsigned hi = *(const unsigned*)(p + 4);
    return (long)(((unsigned long long)hi << 32) | (unsigned long long)lo);
}

// core fragment loads for one site (A-operand of the build MFMAs). L2-hot.
__device__ __forceinline__ void af_load(long af[16], const unsigned char* __restrict__ core8,
                                        int n, int wave, int cl, int q) {
    const unsigned char* base = core8 + (size_t)n * (1024 * FEATD);
#pragma unroll
    for (int i = 0; i < 8; ++i) {
        const unsigned char* p = base + (size_t)((wave * 8 + i) * 16 + cl) * FEATD + q * 8;
        af[2 * i + 0] = *(const long*)p;
        af[2 * i + 1] = *(const long*)(p + 32);
    }
}

// Convert chain accumulator (two I-blocks of one J-column) into the next
// B-operand fragment, in-register. Target lane (cl,q) byte j holds
// value at m = 8q+j, i.e. acc reg g=(m&3) of lane (cl, (m>>2)&3), block I=m>>4.
__device__ __forceinline__ long cvt_frag(float4v c0, float4v c1,
                                         int idxlo, int idxhi, int selhi) {
    const float s = 0.0625f;
    int d0 = (int)pk4_fp8(c0[0] * s, c0[1] * s, c0[2] * s, c0[3] * s);
    int d1 = (int)pk4_fp8(c1[0] * s, c1[1] * s, c1[2] * s, c1[3] * s);
    int l0 = __builtin_amdgcn_ds_bpermute(idxlo, d0);
    int l1 = __builtin_amdgcn_ds_bpermute(idxlo, d1);
    int h0 = __builtin_amdgcn_ds_bpermute(idxhi, d0);
    int h1 = __builtin_amdgcn_ds_bpermute(idxhi, d1);
    unsigned lo = (unsigned)(selhi ? l1 : l0);
    unsigned hi = (unsigned)(selhi ? h1 : h0);
    return (long)(((unsigned long long)hi << 32) | (unsigned long long)lo);
}

// cores [n][d][f][r] fp32 -> core8 [n][c=d*32+r][f] fp8 (x16), LDS transpose.
__global__ __launch_bounds__(256)
void prep_cores8(const float* __restrict__ cores, unsigned char* __restrict__ core8) {
    __shared__ float tile[FEATD][BOND + 4];
    const int nd = blockIdx.x;            // n*32 + d
    const int t  = threadIdx.x;
    const float* src = cores + (size_t)nd * (FEATD * BOND);
    {   // coalesced read of the 64x32 fp32 tile (flat = f*32 + r)
        int base = t * 8;
        int f = base >> 5, r0 = base & 31;
        float4 v0 = *(const float4*)(src + base);
        float4 v1 = *(const float4*)(src + base + 4);
        tile[f][r0 + 0] = v0.x; tile[f][r0 + 1] = v0.y;
        tile[f][r0 + 2] = v0.z; tile[f][r0 + 3] = v0.w;
        tile[f][r0 + 4] = v1.x; tile[f][r0 + 5] = v1.y;
        tile[f][r0 + 6] = v1.z; tile[f][r0 + 7] = v1.w;
    }
    __syncthreads();
    const int r = t >> 3, f0 = (t & 7) * 8;
    const float s = 16.0f;
    unsigned lo = pk4_fp8(tile[f0 + 0][r] * s, tile[f0 + 1][r] * s,
                          tile[f0 + 2][r] * s, tile[f0 + 3][r] * s);
    unsigned hi = pk4_fp8(tile[f0 + 4][r] * s, tile[f0 + 5][r] * s,
                          tile[f0 + 6][r] * s, tile[f0 + 7][r] * s);
    uint2 w; w.x = lo; w.y = hi;
    *(uint2*)(core8 + ((size_t)nd * BOND + r) * FEATD + f0) = w;
}

__global__ __launch_bounds__(512, 4)
void mps_seg(const float* __restrict__ x, const unsigned char* __restrict__ core8,
             unsigned char* __restrict__ Pout) {
    // MA[b][d][r]: M_a, d-major  (A-operand of pair product)
    // MB[b][r][d]: M_b^T, r-major (B-operand of pair product)
    // NT[b][r][d]: N^T, r-major  (A-operand of chain fold)
    __shared__ __align__(16) unsigned char MA[BT * BSTRIDE];
    __shared__ __align__(16) unsigned char MB[BT * BSTRIDE];
    __shared__ __align__(16) unsigned char NT[BT * BSTRIDE];
    __shared__ __align__(16) unsigned char XS[2][2][BT * 72];   // [slot][site][b][f]

    const int t    = threadIdx.x;
    const int wave = t >> 6;
    const int lane = t & 63;
    const int cl   = lane & 15;
    const int q    = lane >> 4;
    const int bt   = blockIdx.x;          // batch tile
    const int seg  = blockIdx.y;
    const int b0   = bt * BT;
    const int xb   = t >> 5, xf = (t & 31) * 2;

    // bpermute source lanes for the acc->B-frag conversion
    const int idxlo = (cl + 16 * ((2 * q) & 3)) << 2;
    const int idxhi = (cl + 16 * ((2 * q + 1) & 3)) << 2;
    const int selhi = q >> 1;

    // running product P (= 16*identity) as B-fragments, per wave's 2 batches
    long ps[2][2];
#pragma unroll
    for (int J = 0; J < 2; ++J) {
        int row = J * 16 + cl;
        int jj  = row - 8 * q;
        long v  = (jj >= 0 && jj < 8) ? (long)(0x58ULL << (8 * jj)) : 0L;
        ps[0][J] = v;
        ps[1][J] = v;
    }

    const int n0 = seg * SEGLEN;

    // prologue: x for pair 0, stage XS slot 0, issue core loads for site 0
    const float* xptr = x + ((size_t)(b0 + xb) * NSITES + n0) * FEATD + xf;
    float2 xa  = *(const float2*)xptr;
    float2 xbv = *(const float2*)(xptr + FEATD);
    {
        int v0 = __builtin_amdgcn_cvt_pk_fp8_f32(xa.x, xa.y, 0, false);
        *(unsigned short*)&XS[0][0][xb * 72 + xf] = (unsigned short)(v0 & 0xffff);
        int v1 = __builtin_amdgcn_cvt_pk_fp8_f32(xbv.x, xbv.y, 0, false);
        *(unsigned short*)&XS[0][1][xb * 72 + xf] = (unsigned short)(v1 & 0xffff);
    }
    long afa[16];
    af_load(afa, core8, n0, wave, cl, q);
    __syncthreads();

    for (int j = 0; j < NPAIR; ++j) {
        const int n = n0 + 2 * j;

        // ---------------- BUILD PHASE: M_a -> MA (d-major), M_b -> MB (r-major)
        {
            const unsigned char* xsA = &XS[j & 1][0][0];
            const unsigned char* xsB = &XS[j & 1][1][0];
            long bxa0 = *(const long*)(xsA + cl * 72 + q * 8);
            long bxa1 = *(const long*)(xsA + cl * 72 + 32 + q * 8);
            long bxb0 = *(const long*)(xsB + cl * 72 + q * 8);
            long bxb1 = *(const long*)(xsB + cl * 72 + 32 + q * 8);

            long afb[16];
            af_load(afb, core8, n + 1, wave, cl, q);   // hides under build_a

            // build site a (even): acc[i][g] = 16*M_a at c=(wave*8+i)*16+4q+g, batch=cl
            float4v acc[8];
#pragma unroll
            for (int i = 0; i < 8; ++i) {
                float4v z = {0.f, 0.f, 0.f, 0.f};
                z = __builtin_amdgcn_mfma_f32_16x16x32_fp8_fp8(afa[2 * i + 0], bxa0, z, 0, 0, 0);
                acc[i] = __builtin_amdgcn_mfma_f32_16x16x32_fp8_fp8(afa[2 * i + 1], bxa1, z, 0, 0, 0);
            }
            // d-major writeback: row d = wave*4+(i>>1), cols r = (i&1)*16+4q+g (pack g)
#pragma unroll
            for (int i = 0; i < 8; ++i) {
                unsigned w = pk4_fp8(acc[i][0], acc[i][1], acc[i][2], acc[i][3]);
                *(unsigned*)&MA[cl * BSTRIDE + (wave * 4 + (i >> 1)) * RSTRIDE
                                + (i & 1) * 16 + q * 4] = w;
            }

            // x prefetch for pair j+1
            if (j + 1 < NPAIR) {
                const float* xp = x + ((size_t)(b0 + xb) * NSITES + n + 2) * FEATD + xf;
                xa  = *(const float2*)xp;
                xbv = *(const float2*)(xp + FEATD);
            }

            // build site b (odd)
            float4v accb[8];
#pragma unroll
            for (int i = 0; i < 8; ++i) {
                float4v z = {0.f, 0.f, 0.f, 0.f};
                z = __builtin_amdgcn_mfma_f32_16x16x32_fp8_fp8(afb[2 * i + 0], bxb0, z, 0, 0, 0);
                accb[i] = __builtin_amdgcn_mfma_f32_16x16x32_fp8_fp8(afb[2 * i + 1], bxb1, z, 0, 0, 0);
            }
            // r-major writeback: row r = 16p+4q+g, cols d = wave*4+u (pack u)
#pragma unroll
            for (int p = 0; p < 2; ++p)
#pragma unroll
                for (int g = 0; g < 4; ++g) {
                    unsigned w = pk4_fp8(accb[0 + p][g], accb[2 + p][g],
                                         accb[4 + p][g], accb[6 + p][g]);
                    *(unsigned*)&MB[cl * BSTRIDE + (16 * p + 4 * q + g) * RSTRIDE
                                    + wave * 4] = w;
                }
        }
        __syncthreads();   // MA/MB visible

        // ---------------- PRODUCT PHASE: N = M_a*M_b -> NT; chain P <- P*N (regs)
        {
            // prefetch/stage for pair j+1 (covers global latency under products)
            if (j + 1 < NPAIR) {
                int v0 = __builtin_amdgcn_cvt_pk_fp8_f32(xa.x, xa.y, 0, false);
                *(unsigned short*)&XS[(j + 1) & 1][0][xb * 72 + xf] = (unsigned short)(v0 & 0xffff);
                int v1 = __builtin_amdgcn_cvt_pk_fp8_f32(xbv.x, xbv.y, 0, false);
                *(unsigned short*)&XS[(j + 1) & 1][1][xb * 72 + xf] = (unsigned short)(v1 & 0xffff);
                af_load(afa, core8, n + 2, wave, cl, q);
            }

            // pair product, wave owns batches 2w, 2w+1
#pragma unroll
            for (int bi = 0; bi < 2; ++bi) {
                const int bb = wave * 2 + bi;
                const unsigned char* mab = &MA[bb * BSTRIDE];
                const unsigned char* mbb = &MB[bb * BSTRIDE];
                long pa0 = ld8(mab + cl * RSTRIDE + q * 8);
                long pa1 = ld8(mab + (16 + cl) * RSTRIDE + q * 8);
                long pb0 = ld8(mbb + cl * RSTRIDE + q * 8);
                long pb1 = ld8(mbb + (16 + cl) * RSTRIDE + q * 8);
                float4v z00 = {0.f, 0.f, 0.f, 0.f}, z01 = {0.f, 0.f, 0.f, 0.f};
                float4v z10 = {0.f, 0.f, 0.f, 0.f}, z11 = {0.f, 0.f, 0.f, 0.f};
                z00 = __builtin_amdgcn_mfma_f32_16x16x32_fp8_fp8(pa0, pb0, z00, 0, 0, 0);
                z01 = __builtin_amdgcn_mfma_f32_16x16x32_fp8_fp8(pa0, pb1, z01, 0, 0, 0);
                z10 = __builtin_amdgcn_mfma_f32_16x16x32_fp8_fp8(pa1, pb0, z10, 0, 0, 0);
                z11 = __builtin_amdgcn_mfma_f32_16x16x32_fp8_fp8(pa1, pb1, z11, 0, 0, 0);
                // std writeback -> NT[r=16J+cl][d=16I+4q+g] = 16*N^T  (scale 1/16)
                unsigned char* nb = &NT[bb * BSTRIDE];
                const float s = 0.0625f;
                unsigned w00 = pk4_fp8(z00[0] * s, z00[1] * s, z00[2] * s, z00[3] * s);
                unsigned w01 = pk4_fp8(z01[0] * s, z01[1] * s, z01[2] * s, z01[3] * s);
                unsigned w10 = pk4_fp8(z10[0] * s, z10[1] * s, z10[2] * s, z10[3] * s);
                unsigned w11 = pk4_fp8(z11[0] * s, z11[1] * s, z11[2] * s, z11[3] * s);
                *(unsigned*)&nb[(0 * 16 + cl) * RSTRIDE + 0 * 16 + q * 4] = w00;   // I=0,J=0
                *(unsigned*)&nb[(1 * 16 + cl) * RSTRIDE + 0 * 16 + q * 4] = w01;   // I=0,J=1
                *(unsigned*)&nb[(0 * 16 + cl) * RSTRIDE + 1 * 16 + q * 4] = w10;   // I=1,J=0
                *(unsigned*)&nb[(1 * 16 + cl) * RSTRIDE + 1 * 16 + q * 4] = w11;   // I=1,J=1
            }

            // chain fold: P^T_new = N^T * P^T  (A from NT, B = ps regs), same wave
#pragma unroll
            for (int bi = 0; bi < 2; ++bi) {
                const int bb = wave * 2 + bi;
                const unsigned char* nb = &NT[bb * BSTRIDE];
                long ca0 = ld8(nb + cl * RSTRIDE + q * 8);
                long ca1 = ld8(nb + (16 + cl) * RSTRIDE + q * 8);
                float4v c00 = {0.f, 0.f, 0.f, 0.f}, c01 = {0.f, 0.f, 0.f, 0.f};
                float4v c10 = {0.f, 0.f, 0.f, 0.f}, c11 = {0.f, 0.f, 0.f, 0.f};
                c00 = __builtin_amdgcn_mfma_f32_16x16x32_fp8_fp8(ca0, ps[bi][0], c00, 0, 0, 0);
                c01 = __builtin_amdgcn_mfma_f32_16x16x32_fp8_fp8(ca0, ps[bi][1], c01, 0, 0, 0);
                c10 = __builtin_amdgcn_mfma_f32_16x16x32_fp8_fp8(ca1, ps[bi][0], c10, 0, 0, 0);
                c11 = __builtin_amdgcn_mfma_f32_16x16x32_fp8_fp8(ca1, ps[bi][1], c11, 0, 0, 0);
                ps[bi][0] = cvt_frag(c00, c10, idxlo, idxhi, selhi);
                ps[bi][1] = cvt_frag(c01, c11, idxlo, idxhi, selhi);
            }
        }
        __syncthreads();   // MA/MB free for next pair
    }

    // dump P (=16*segment product) regs -> Pout[seg][b][d*32+r]
#pragma unroll
    for (int bi = 0; bi < 2; ++bi) {
        const int bb = wave * 2 + bi;
        unsigned char* gp = Pout + ((size_t)seg * 2048 + b0 + bb) * 1024;
#pragma unroll
        for (int J = 0; J < 2; ++J)
            *(long*)(gp + (J * 16 + cl) * 32 + q * 8) = ps[bi][J];
    }
}

__global__ __launch_bounds__(256)
void combine(const unsigned char* __restrict__ Pout, const float* __restrict__ startv,
             const float* __restrict__ endv, const float* __restrict__ fc_w,
             const float* __restrict__ fc_b, float* __restrict__ out) {
    __shared__ __align__(16) unsigned char st[8 * 1024];
    __shared__ float resA[8][33], resB[8][33];
    __shared__ float val[8];
    const int t  = threadIdx.x;
    const int b0 = blockIdx.x * 8;
    const int bb = t >> 5, r = t & 31;

    resA[bb][r] = startv[r];
    for (int s = 0; s < NSEG; ++s) {
        {   // stage 8 KB (8 batches x 1 KB), coalesced
            const uint4* g = (const uint4*)(Pout + ((size_t)s * 2048 + b0) * 1024 + (size_t)t * 32);
            uint4* p = (uint4*)&st[t * 32];
            p[0] = g[0];
            p[1] = g[1];
        }
        __syncthreads();
        const float* rin = (s & 1) ? &resB[bb][0] : &resA[bb][0];
        float* rout      = (s & 1) ? &resA[bb][0] : &resB[bb][0];
        float acc = 0.f;
#pragma unroll
        for (int d = 0; d < BOND; ++d) {
            int byte = st[bb * 1024 + d * 32 + r];
            acc += rin[d] * __builtin_amdgcn_cvt_f32_fp8(byte, 0);
        }
        rout[r] = acc * 0.0625f;
        __syncthreads();
    }
    // NSEG even -> result in resA
    float prod = resA[bb][r] * endv[r];
#pragma unroll
    for (int off = 16; off >= 1; off >>= 1) prod += __shfl_down(prod, off, 32);
    if (r == 0) val[bb] = prod;
    __syncthreads();

    const float v = val[t >> 5];
    const int j0 = (t & 31) * 8;
    const int ob = b0 + (t >> 5);
#pragma unroll
    for (int i = 0; i < 2; ++i) {
        int j = j0 + i * 4;
        float4 w4 = *(const float4*)(fc_w + j);
        float4 bbv = *(const float4*)(fc_b + j);
        float4 o;
        o.x = v * w4.x + bbv.x;
        o.y = v * w4.y + bbv.y;
        o.z = v * w4.z + bbv.z;
        o.w = v * w4.w + bbv.w;
        *(float4*)(out + (size_t)ob * OUTD + j) = o;
    }
}

extern "C" void kernel_launch(void* const* d_in, const int* in_sizes, int n_in,
                              void* d_out, int out_size, void* d_ws, size_t ws_size,
                              hipStream_t stream) {
    const float* x      = (const float*)d_in[0];
    const float* cores  = (const float*)d_in[1];
    const float* startv = (const float*)d_in[2];
    const float* endv   = (const float*)d_in[3];
    const float* fc_w   = (const float*)d_in[4];
    const float* fc_b   = (const float*)d_in[5];
    float* out = (float*)d_out;

    unsigned char* core8 = (unsigned char*)d_ws;                       // 8.4 MB
    unsigned char* Pout  = core8 + (size_t)NSITES * 1024 * FEATD;      // 16.8 MB

    prep_cores8<<<NSITES * BOND, 256, 0, stream>>>(cores, core8);
    mps_seg<<<dim3(NBT, NSEG), 512, 0, stream>>>(x, core8, Pout);
    combine<<<2048 / 8, 256, 0, stream>>>(Pout, startv, endv, fc_w, fc_b, out);
}